// Round 4
// baseline (1531.589 us; speedup 1.0000x reference)
//
#include <hip/hip_runtime.h>
#include <hip/hip_bf16.h>
#include <cstdint>

// Problem constants (B,S,E,H) = (4, 2048, 256, 8), fp32 in/out.
#define B_N 4
#define S_N 2048
#define E_N 256
#define H_N 8

typedef float f32x4 __attribute__((ext_vector_type(4)));
typedef short s16x8 __attribute__((ext_vector_type(8)));   // 8 bf16 as shorts (4 VGPR)

static __device__ __forceinline__ f32x4 mfma16(s16x8 a, s16x8 b, f32x4 c) {
  return __builtin_amdgcn_mfma_f32_16x16x32_bf16(a, b, c, 0, 0, 0);
}

// fp32 <-> bf16 (RNE) bit ops.
static __device__ __forceinline__ unsigned short f2bf(float f) {
  union { float f; unsigned int u; } v; v.f = f;
  unsigned int r = v.u + 0x7fffu + ((v.u >> 16) & 1u);
  return (unsigned short)(r >> 16);
}
static __device__ __forceinline__ float bf2f(unsigned short s) {
  union { unsigned int u; float f; } v; v.u = ((unsigned int)s) << 16;
  return v.f;
}
static __device__ __forceinline__ unsigned short f2bf_fast(float f) {
  __hip_bfloat16 h = __float2bfloat16(f);
  return *(unsigned short*)&h;
}

// Async global->LDS, 16B per lane. LDS dest: wave-uniform base + lane*16.
static __device__ __forceinline__ void gload16(const void* g, void* l) {
  __builtin_amdgcn_global_load_lds(
      (const __attribute__((address_space(1))) unsigned int*)g,
      (__attribute__((address_space(3))) unsigned int*)l, 16, 0, 0);
}

// 16-lane (DPP-row) butterfly reduces — pure VALU, no LDS unit.
static __device__ __forceinline__ float dppmax16(float x) {
  x = fmaxf(x, __int_as_float(__builtin_amdgcn_update_dpp(
          0, __float_as_int(x), 0xB1, 0xF, 0xF, true)));   // xor 1 (quad_perm 1,0,3,2)
  x = fmaxf(x, __int_as_float(__builtin_amdgcn_update_dpp(
          0, __float_as_int(x), 0x4E, 0xF, 0xF, true)));   // xor 2 (quad_perm 2,3,0,1)
  x = fmaxf(x, __int_as_float(__builtin_amdgcn_update_dpp(
          0, __float_as_int(x), 0x141, 0xF, 0xF, true)));  // xor 4 (row_half_mirror)
  x = fmaxf(x, __int_as_float(__builtin_amdgcn_update_dpp(
          0, __float_as_int(x), 0x140, 0xF, 0xF, true)));  // xor 8 (row_mirror)
  return x;
}
static __device__ __forceinline__ float dppsum16(float x) {
  x = x + __int_as_float(__builtin_amdgcn_update_dpp(
          0, __float_as_int(x), 0xB1, 0xF, 0xF, true));
  x = x + __int_as_float(__builtin_amdgcn_update_dpp(
          0, __float_as_int(x), 0x4E, 0xF, 0xF, true));
  x = x + __int_as_float(__builtin_amdgcn_update_dpp(
          0, __float_as_int(x), 0x141, 0xF, 0xF, true));
  x = x + __int_as_float(__builtin_amdgcn_update_dpp(
          0, __float_as_int(x), 0x140, 0xF, 0xF, true));
  return x;
}

// ---------------------------------------------------------------------------
// Split fp32 -> bf16 hi + bf16 lo.
__global__ void k_split(const float* __restrict__ src, unsigned short* __restrict__ hi,
                        unsigned short* __restrict__ lo, int n4) {
  int i = blockIdx.x * blockDim.x + threadIdx.x;
  if (i >= n4) return;
  float4 v = ((const float4*)src)[i];
  float f[4] = {v.x, v.y, v.z, v.w};
  unsigned short hh[4], ll[4];
#pragma unroll
  for (int j = 0; j < 4; j++) {
    hh[j] = f2bf(f[j]);
    ll[j] = f2bf(f[j] - bf2f(hh[j]));
  }
  ushort4 h; h.x = hh[0]; h.y = hh[1]; h.z = hh[2]; h.w = hh[3];
  ushort4 l; l.x = ll[0]; l.y = ll[1]; l.z = ll[2]; l.w = ll[3];
  ((ushort4*)hi)[i] = h;
  ((ushort4*)lo)[i] = l;
}

// ---------------------------------------------------------------------------
// WvT[h][f][e] = bf16(Wv[h][e][f])
__global__ void k_transpose_wv(const float* __restrict__ wv, unsigned short* __restrict__ wvT) {
  __shared__ float t[32][33];
  int h = blockIdx.z;
  int e0 = blockIdx.x * 32, f0 = blockIdx.y * 32;
  int tx = threadIdx.x & 31, ty = threadIdx.x >> 5;
  const float* src = wv + ((size_t)h * E_N + e0) * E_N + f0;
#pragma unroll
  for (int r = ty; r < 32; r += 8) t[r][tx] = src[(size_t)r * E_N + tx];
  __syncthreads();
  unsigned short* dst = wvT + ((size_t)h * E_N + f0) * E_N + e0;
#pragma unroll
  for (int r = ty; r < 32; r += 8) dst[(size_t)r * E_N + tx] = f2bf(t[tx][r]);
}

// ---------------------------------------------------------------------------
// bt-GEMM: C[m,n] = sum_k A[m,k]*B[n,k], 128x128 tile, BK=32, 4 waves.
#define BKP 40  // 32 + 8 pad

template <int TERMS, int SPLIT_OUT>
__global__ __launch_bounds__(256, 2) void k_gemm(
    const unsigned short* __restrict__ Ahi, const unsigned short* __restrict__ Alo,
    const unsigned short* __restrict__ Bhi, const unsigned short* __restrict__ Blo,
    unsigned short* __restrict__ Chi, unsigned short* __restrict__ Clo,
    int K, int N,
    int aDiv, int aMod, long long aStr,
    int bDiv, int bMod, long long bStr,
    long long cStr) {
  __shared__ unsigned short sA[2][128 * BKP];
  __shared__ unsigned short sB[2][128 * BKP];
  int z = blockIdx.z;
  const unsigned short* A0h = Ahi + (long long)((z / aDiv) % aMod) * aStr;
  const unsigned short* A0l = Alo + (long long)((z / aDiv) % aMod) * aStr;
  const unsigned short* B0h = Bhi + (long long)((z / bDiv) % bMod) * bStr;
  const unsigned short* B0l = Blo + (long long)((z / bDiv) % bMod) * bStr;
  int rT = blockIdx.x * 128, cT = blockIdx.y * 128;
  int tid = threadIdx.x;
  int w = tid >> 6, l = tid & 63, lr = l & 15, lg = l >> 4;
  int wr = w >> 1, wc = w & 1;

  f32x4 acc[4][4];
#pragma unroll
  for (int i = 0; i < 4; i++)
#pragma unroll
    for (int j = 0; j < 4; j++) acc[i][j] = (f32x4){0.f, 0.f, 0.f, 0.f};

  for (int k0 = 0; k0 < K; k0 += 32) {
#pragma unroll
    for (int it = 0; it < 2; it++) {
      int idx = (it * 256 + tid) * 8;
      int r = idx >> 5, c = idx & 31;
      *(s16x8*)&sA[0][r * BKP + c] = *(const s16x8*)(A0h + (size_t)(rT + r) * K + k0 + c);
      *(s16x8*)&sB[0][r * BKP + c] = *(const s16x8*)(B0h + (size_t)(cT + r) * K + k0 + c);
      if (TERMS == 3) {
        *(s16x8*)&sA[1][r * BKP + c] = *(const s16x8*)(A0l + (size_t)(rT + r) * K + k0 + c);
        *(s16x8*)&sB[1][r * BKP + c] = *(const s16x8*)(B0l + (size_t)(cT + r) * K + k0 + c);
      }
    }
    __syncthreads();
    s16x8 ah[4], al[4], bh[4], bl[4];
#pragma unroll
    for (int i = 0; i < 4; i++) {
      ah[i] = *(const s16x8*)&sA[0][(wr * 64 + i * 16 + lr) * BKP + lg * 8];
      if (TERMS == 3) al[i] = *(const s16x8*)&sA[1][(wr * 64 + i * 16 + lr) * BKP + lg * 8];
    }
#pragma unroll
    for (int j = 0; j < 4; j++) {
      bh[j] = *(const s16x8*)&sB[0][(wc * 64 + j * 16 + lr) * BKP + lg * 8];
      if (TERMS == 3) bl[j] = *(const s16x8*)&sB[1][(wc * 64 + j * 16 + lr) * BKP + lg * 8];
    }
#pragma unroll
    for (int i = 0; i < 4; i++)
#pragma unroll
      for (int j = 0; j < 4; j++) {
        acc[i][j] = mfma16(ah[i], bh[j], acc[i][j]);
        if (TERMS == 3) {
          acc[i][j] = mfma16(ah[i], bl[j], acc[i][j]);
          acc[i][j] = mfma16(al[i], bh[j], acc[i][j]);
        }
      }
    __syncthreads();
  }
  long long cOff = (long long)z * cStr;
#pragma unroll
  for (int i = 0; i < 4; i++)
#pragma unroll
    for (int j = 0; j < 4; j++)
#pragma unroll
      for (int r = 0; r < 4; r++) {
        int row = rT + wr * 64 + i * 16 + lg * 4 + r;  // C/D: row=(l>>4)*4+reg
        int col = cT + wc * 64 + j * 16 + lr;          //      col=l&15
        float v = acc[i][j][r];
        unsigned short hb = f2bf(v);
        Chi[cOff + (size_t)row * N + col] = hb;
        if (SPLIT_OUT) Clo[cOff + (size_t)row * N + col] = f2bf(v - bf2f(hb));
      }
}

// ---------------------------------------------------------------------------
// Fused flash attention, round 4: 4-wave blocks (64 q-rows), TT=32 kv-tiles,
// 52 KB LDS -> 3 blocks/CU = 3 independent barrier domains (phase diversity).
// LDS map:
//   [0,16384)       X hi [32 t][512B], rows swizzled ^((row&7)<<4)
//   [16384,32768)   X lo
//   [32768,49152)   VT  [256 f][64B],  rows swizzled ^(((row>>1)&3)<<4)
//   [49152,53248)   P: per wave 1KB [16 q][64B], swizzled like VT
// DPP softmax reduces; sum-reduce deferred to epilogue; max-reduce only in
// the (rare) rescale branch.
#define TT 32
#define ATTN_LDS 53248

__global__ __launch_bounds__(256, 3) void k_attn(
    const unsigned short* __restrict__ Yhi, const unsigned short* __restrict__ Ylo,
    const unsigned short* __restrict__ Xhi, const unsigned short* __restrict__ Xlo,
    const unsigned short* __restrict__ VT, float* __restrict__ Out) {
  extern __shared__ char smem[];

  // XCD-chunked bijective swizzle: 1024 blocks = 8 XCD * 128; chunk = 4 bh.
  int obid = blockIdx.x;
  int swz = (obid & 7) * 128 + (obid >> 3);
  int qt = swz & 31, bh = swz >> 5;
  int b = bh >> 3;
  int tid = threadIdx.x, w = tid >> 6, l = tid & 63, lr = l & 15, lg = l >> 4;
  const unsigned short* Ybh_h = Yhi + (size_t)bh * (S_N * E_N);
  const unsigned short* Ybh_l = Ylo + (size_t)bh * (S_N * E_N);
  const unsigned short* Xb_h = Xhi + (size_t)b * (S_N * E_N);
  const unsigned short* Xb_l = Xlo + (size_t)b * (S_N * E_N);
  const unsigned short* Vbh = VT + (size_t)bh * (E_N * S_N);
  int qrow = qt * 64 + w * 16;

  // Per-lane staging descriptors (inverse-swizzled global element offsets).
  int xoff[4], voff[4], xlds[4], vlds[4];
#pragma unroll
  for (int i = 0; i < 4; i++) {
    int c = w * 4 + i;
    int rx = 2 * c + (l >> 5), bx = (l & 31) * 16;
    xoff[i] = rx * E_N + ((bx ^ ((rx & 7) << 4)) >> 1);
    xlds[i] = c * 1024;
    int rv = 16 * c + (l >> 2), bv = (l & 3) * 16;
    voff[i] = rv * S_N + ((bv ^ (((rv >> 1) & 3) << 4)) >> 1);
    vlds[i] = 32768 + c * 1024;
  }
  char* sPw = smem + 49152 + w * 1024;

  // Hoist Y fragments (16 rows x K=256, hi+lo) into registers.
  s16x8 yh[8], yl[8];
#pragma unroll
  for (int kc = 0; kc < 8; kc++) {
    yh[kc] = *(const s16x8*)(Ybh_h + (size_t)(qrow + lr) * E_N + kc * 32 + lg * 8);
    yl[kc] = *(const s16x8*)(Ybh_l + (size_t)(qrow + lr) * E_N + kc * 32 + lg * 8);
  }
  f32x4 o[16];
#pragma unroll
  for (int i = 0; i < 16; i++) o[i] = (f32x4){0.f, 0.f, 0.f, 0.f};
  float m2[4], lv[4];
#pragma unroll
  for (int r = 0; r < 4; r++) { m2[r] = -3.0e38f; lv[r] = 0.f; }

  const float C2 = 0.09016844005556021f;  // (1/16) * log2(e)

  for (int kt = 0; kt < S_N / TT; kt++) {
    __builtin_amdgcn_s_barrier();  // B1: all waves done reading previous tile

    // Stage X[kt] (hi+lo) and VT[kt] via async global->LDS.
#pragma unroll
    for (int i = 0; i < 4; i++) {
      gload16(Xb_h + (size_t)kt * (TT * E_N) + xoff[i], smem + xlds[i]);
      gload16(Xb_l + (size_t)kt * (TT * E_N) + xoff[i], smem + 16384 + xlds[i]);
      gload16(Vbh + kt * TT + voff[i], smem + vlds[i]);
    }
    asm volatile("s_waitcnt vmcnt(0)" ::: "memory");
    __builtin_amdgcn_s_barrier();  // B2: staged data visible to all waves

    // S = Y . X^T (3-term split), raw units.
    f32x4 sc[2];
    __builtin_amdgcn_s_setprio(1);
#pragma unroll
    for (int j = 0; j < 2; j++) {
      f32x4 a = (f32x4){0.f, 0.f, 0.f, 0.f};
#pragma unroll
      for (int kc = 0; kc < 8; kc++) {
        int ad = (j * 16 + lr) * 512 + ((kc * 64 + lg * 16) ^ ((lr & 7) << 4));
        s16x8 xh = *(const s16x8*)(smem + ad);
        s16x8 xl = *(const s16x8*)(smem + 16384 + ad);
        a = mfma16(yh[kc], xh, a);
        a = mfma16(yh[kc], xl, a);
        a = mfma16(yl[kc], xh, a);
      }
      sc[j] = a;
    }
    __builtin_amdgcn_s_setprio(0);

    // Online softmax, log2 domain. Lane holds rows lg*4+r, cols j*16+lr.
    float t2[4];
#pragma unroll
    for (int r = 0; r < 4; r++) t2[r] = fmaxf(sc[0][r], sc[1][r]) * C2;

    // Defer-max via per-lane partial check (equivalent under __all).
    bool ok = (t2[0] <= m2[0] + 8.f) && (t2[1] <= m2[1] + 8.f) &&
              (t2[2] <= m2[2] + 8.f) && (t2[3] <= m2[3] + 8.f);
    if (!__all(ok)) {
      float fr[4];
#pragma unroll
      for (int r = 0; r < 4; r++) {
        float rm = dppmax16(t2[r]);          // true row max
        float nm = fmaxf(m2[r], rm);
        fr[r] = exp2f(m2[r] - nm);
        m2[r] = nm;
        lv[r] *= fr[r];
      }
#pragma unroll
      for (int i = 0; i < 16; i++)
#pragma unroll
        for (int r = 0; r < 4; r++) o[i][r] *= fr[r];
    }

    float p[2][4];
#pragma unroll
    for (int j = 0; j < 2; j++)
#pragma unroll
      for (int r = 0; r < 4; r++)
        p[j][r] = exp2f(fmaf(sc[j][r], C2, -m2[r]));
#pragma unroll
    for (int r = 0; r < 4; r++) lv[r] += p[0][r] + p[1][r];  // per-lane partial

    // P -> LDS bf16 (wave-private, swizzled rows of 64B).
#pragma unroll
    for (int j = 0; j < 2; j++)
#pragma unroll
      for (int r = 0; r < 4; r++) {
        int row = lg * 4 + r;
        int off = ((j * 16 + lr) * 2) ^ ((((row & 7) >> 1) & 3) << 4);
        *(unsigned short*)(sPw + row * 64 + off) = f2bf_fast(p[j][r]);
      }

    // O += P . VT  (bt-form; K = TT = 32 in one MFMA k-pass)
    __builtin_amdgcn_s_setprio(1);
    int ap = lr * 64 + ((lg * 16) ^ (((lr >> 1) & 3) << 4));
    s16x8 pa = *(const s16x8*)(sPw + ap);
#pragma unroll
    for (int jf = 0; jf < 16; jf++) {
      int ad = (jf * 16 + lr) * 64 + ((lg * 16) ^ (((lr >> 1) & 3) << 4));
      s16x8 bv = *(const s16x8*)(smem + 32768 + ad);
      o[jf] = mfma16(pa, bv, o[jf]);
    }
    __builtin_amdgcn_s_setprio(0);
  }

  // Epilogue: finish the lv sum-reduce, normalize, head-mean via atomics.
#pragma unroll
  for (int r = 0; r < 4; r++) lv[r] = dppsum16(lv[r]);
#pragma unroll
  for (int jf = 0; jf < 16; jf++)
#pragma unroll
    for (int r = 0; r < 4; r++) {
      float v = o[jf][r] / lv[r] * 0.125f;
      atomicAdd(&Out[((size_t)b * S_N + qrow + lg * 4 + r) * E_N + jf * 16 + lr], v);
    }
}

// ---------------------------------------------------------------------------
extern "C" void kernel_launch(void* const* d_in, const int* in_sizes, int n_in,
                              void* d_out, int out_size, void* d_ws, size_t ws_size,
                              hipStream_t stream) {
  const float* x = (const float*)d_in[0];
  const float* wq = (const float*)d_in[1];
  const float* wk = (const float*)d_in[2];
  const float* wv = (const float*)d_in[3];
  float* out = (float*)d_out;

  unsigned short* ws = (unsigned short*)d_ws;
  unsigned short* x_hi = ws;                       // [B,S,E]
  unsigned short* x_lo = x_hi + 2097152;
  unsigned short* wq_hi = x_lo + 2097152;          // [H,E,E]
  unsigned short* wq_lo = wq_hi + 524288;
  unsigned short* wk_hi = wq_lo + 524288;
  unsigned short* wk_lo = wk_hi + 524288;
  unsigned short* wvT = wk_lo + 524288;            // [H,E(f),E(e)]
  unsigned short* mt_hi = wvT + 524288;            // [H,E,E] = Wk.Wq^T
  unsigned short* mt_lo = mt_hi + 524288;
  unsigned short* y_hi = mt_lo + 524288;           // [B,H,S,E]
  unsigned short* y_lo = y_hi + 16777216;
  unsigned short* vt = y_lo + 16777216;            // [B,H,E(f),S(t)]

  hipMemsetAsync(d_out, 0, (size_t)out_size * sizeof(float), stream);

  k_split<<<2048, 256, 0, stream>>>(x, x_hi, x_lo, 524288);
  k_split<<<512, 256, 0, stream>>>(wq, wq_hi, wq_lo, 131072);
  k_split<<<512, 256, 0, stream>>>(wk, wk_hi, wk_lo, 131072);
  k_transpose_wv<<<dim3(8, 8, 8), 256, 0, stream>>>(wv, wvT);

  // MT_h = Wk_h . Wq_h^T
  k_gemm<3, 1><<<dim3(2, 2, 8), 256, 0, stream>>>(
      wk_hi, wk_lo, wq_hi, wq_lo, mt_hi, mt_lo, 256, 256,
      1, 8, 65536LL, 1, 8, 65536LL, 65536LL);
  // Y[b,h] = X_b . MT_h^T
  k_gemm<3, 1><<<dim3(16, 2, 32), 256, 0, stream>>>(
      x_hi, x_lo, mt_hi, mt_lo, y_hi, y_lo, 256, 256,
      8, 4, 524288LL, 1, 8, 65536LL, 524288LL);
  // VT[b,h] = WvT_h . X_b^T
  k_gemm<1, 0><<<dim3(2, 16, 32), 256, 0, stream>>>(
      wvT, wvT, x_hi, x_hi, vt, vt, 256, 2048,
      1, 8, 65536LL, 8, 4, 524288LL, 524288LL);

  hipFuncSetAttribute((const void*)k_attn, hipFuncAttributeMaxDynamicSharedMemorySize,
                      ATTN_LDS);
  k_attn<<<dim3(1024), 256, ATTN_LDS, stream>>>(y_hi, y_lo, x_hi, x_lo, vt, out);
}

// Round 5
// 451.346 us; speedup vs baseline: 3.3934x; 3.3934x over previous
//
#include <hip/hip_runtime.h>
#include <hip/hip_bf16.h>
#include <cstdint>

// Problem constants (B,S,E,H) = (4, 2048, 256, 8), fp32 in/out.
#define B_N 4
#define S_N 2048
#define E_N 256
#define H_N 8

typedef float f32x4 __attribute__((ext_vector_type(4)));
typedef short s16x8 __attribute__((ext_vector_type(8)));   // 8 bf16 as shorts (4 VGPR)

static __device__ __forceinline__ f32x4 mfma16(s16x8 a, s16x8 b, f32x4 c) {
  return __builtin_amdgcn_mfma_f32_16x16x32_bf16(a, b, c, 0, 0, 0);
}

// fp32 <-> bf16 (RNE) bit ops.
static __device__ __forceinline__ unsigned short f2bf(float f) {
  union { float f; unsigned int u; } v; v.f = f;
  unsigned int r = v.u + 0x7fffu + ((v.u >> 16) & 1u);
  return (unsigned short)(r >> 16);
}
static __device__ __forceinline__ float bf2f(unsigned short s) {
  union { unsigned int u; float f; } v; v.u = ((unsigned int)s) << 16;
  return v.f;
}
static __device__ __forceinline__ unsigned short f2bf_fast(float f) {
  __hip_bfloat16 h = __float2bfloat16(f);
  return *(unsigned short*)&h;
}

// Async global->LDS, 16B per lane. LDS dest: wave-uniform base + lane*16.
static __device__ __forceinline__ void gload16(const void* g, void* l) {
  __builtin_amdgcn_global_load_lds(
      (const __attribute__((address_space(1))) unsigned int*)g,
      (__attribute__((address_space(3))) unsigned int*)l, 16, 0, 0);
}

// 16-lane (DPP-row) butterfly reduces — pure VALU, no LDS unit.
static __device__ __forceinline__ float dppmax16(float x) {
  x = fmaxf(x, __int_as_float(__builtin_amdgcn_update_dpp(
          0, __float_as_int(x), 0xB1, 0xF, 0xF, true)));   // xor 1
  x = fmaxf(x, __int_as_float(__builtin_amdgcn_update_dpp(
          0, __float_as_int(x), 0x4E, 0xF, 0xF, true)));   // xor 2
  x = fmaxf(x, __int_as_float(__builtin_amdgcn_update_dpp(
          0, __float_as_int(x), 0x141, 0xF, 0xF, true)));  // xor 4
  x = fmaxf(x, __int_as_float(__builtin_amdgcn_update_dpp(
          0, __float_as_int(x), 0x140, 0xF, 0xF, true)));  // xor 8
  return x;
}
static __device__ __forceinline__ float dppsum16(float x) {
  x = x + __int_as_float(__builtin_amdgcn_update_dpp(
          0, __float_as_int(x), 0xB1, 0xF, 0xF, true));
  x = x + __int_as_float(__builtin_amdgcn_update_dpp(
          0, __float_as_int(x), 0x4E, 0xF, 0xF, true));
  x = x + __int_as_float(__builtin_amdgcn_update_dpp(
          0, __float_as_int(x), 0x141, 0xF, 0xF, true));
  x = x + __int_as_float(__builtin_amdgcn_update_dpp(
          0, __float_as_int(x), 0x140, 0xF, 0xF, true));
  return x;
}

// ---------------------------------------------------------------------------
// Split fp32 -> bf16 hi + bf16 lo.
__global__ void k_split(const float* __restrict__ src, unsigned short* __restrict__ hi,
                        unsigned short* __restrict__ lo, int n4) {
  int i = blockIdx.x * blockDim.x + threadIdx.x;
  if (i >= n4) return;
  float4 v = ((const float4*)src)[i];
  float f[4] = {v.x, v.y, v.z, v.w};
  unsigned short hh[4], ll[4];
#pragma unroll
  for (int j = 0; j < 4; j++) {
    hh[j] = f2bf(f[j]);
    ll[j] = f2bf(f[j] - bf2f(hh[j]));
  }
  ushort4 h; h.x = hh[0]; h.y = hh[1]; h.z = hh[2]; h.w = hh[3];
  ushort4 l; l.x = ll[0]; l.y = ll[1]; l.z = ll[2]; l.w = ll[3];
  ((ushort4*)hi)[i] = h;
  ((ushort4*)lo)[i] = l;
}

// ---------------------------------------------------------------------------
// WvT[h][f][e] = bf16(Wv[h][e][f])
__global__ void k_transpose_wv(const float* __restrict__ wv, unsigned short* __restrict__ wvT) {
  __shared__ float t[32][33];
  int h = blockIdx.z;
  int e0 = blockIdx.x * 32, f0 = blockIdx.y * 32;
  int tx = threadIdx.x & 31, ty = threadIdx.x >> 5;
  const float* src = wv + ((size_t)h * E_N + e0) * E_N + f0;
#pragma unroll
  for (int r = ty; r < 32; r += 8) t[r][tx] = src[(size_t)r * E_N + tx];
  __syncthreads();
  unsigned short* dst = wvT + ((size_t)h * E_N + f0) * E_N + e0;
#pragma unroll
  for (int r = ty; r < 32; r += 8) dst[(size_t)r * E_N + tx] = f2bf(t[tx][r]);
}

// ---------------------------------------------------------------------------
// bt-GEMM: C[m,n] = sum_k A[m,k]*B[n,k], 128x128 tile, BK=32, 4 waves.
#define BKP 40  // 32 + 8 pad

template <int TERMS, int SPLIT_OUT>
__global__ __launch_bounds__(256, 2) void k_gemm(
    const unsigned short* __restrict__ Ahi, const unsigned short* __restrict__ Alo,
    const unsigned short* __restrict__ Bhi, const unsigned short* __restrict__ Blo,
    unsigned short* __restrict__ Chi, unsigned short* __restrict__ Clo,
    int K, int N,
    int aDiv, int aMod, long long aStr,
    int bDiv, int bMod, long long bStr,
    long long cStr) {
  __shared__ unsigned short sA[2][128 * BKP];
  __shared__ unsigned short sB[2][128 * BKP];
  int z = blockIdx.z;
  const unsigned short* A0h = Ahi + (long long)((z / aDiv) % aMod) * aStr;
  const unsigned short* A0l = Alo + (long long)((z / aDiv) % aMod) * aStr;
  const unsigned short* B0h = Bhi + (long long)((z / bDiv) % bMod) * bStr;
  const unsigned short* B0l = Blo + (long long)((z / bDiv) % bMod) * bStr;
  int rT = blockIdx.x * 128, cT = blockIdx.y * 128;
  int tid = threadIdx.x;
  int w = tid >> 6, l = tid & 63, lr = l & 15, lg = l >> 4;
  int wr = w >> 1, wc = w & 1;

  f32x4 acc[4][4];
#pragma unroll
  for (int i = 0; i < 4; i++)
#pragma unroll
    for (int j = 0; j < 4; j++) acc[i][j] = (f32x4){0.f, 0.f, 0.f, 0.f};

  for (int k0 = 0; k0 < K; k0 += 32) {
#pragma unroll
    for (int it = 0; it < 2; it++) {
      int idx = (it * 256 + tid) * 8;
      int r = idx >> 5, c = idx & 31;
      *(s16x8*)&sA[0][r * BKP + c] = *(const s16x8*)(A0h + (size_t)(rT + r) * K + k0 + c);
      *(s16x8*)&sB[0][r * BKP + c] = *(const s16x8*)(B0h + (size_t)(cT + r) * K + k0 + c);
      if (TERMS == 3) {
        *(s16x8*)&sA[1][r * BKP + c] = *(const s16x8*)(A0l + (size_t)(rT + r) * K + k0 + c);
        *(s16x8*)&sB[1][r * BKP + c] = *(const s16x8*)(B0l + (size_t)(cT + r) * K + k0 + c);
      }
    }
    __syncthreads();
    s16x8 ah[4], al[4], bh[4], bl[4];
#pragma unroll
    for (int i = 0; i < 4; i++) {
      ah[i] = *(const s16x8*)&sA[0][(wr * 64 + i * 16 + lr) * BKP + lg * 8];
      if (TERMS == 3) al[i] = *(const s16x8*)&sA[1][(wr * 64 + i * 16 + lr) * BKP + lg * 8];
    }
#pragma unroll
    for (int j = 0; j < 4; j++) {
      bh[j] = *(const s16x8*)&sB[0][(wc * 64 + j * 16 + lr) * BKP + lg * 8];
      if (TERMS == 3) bl[j] = *(const s16x8*)&sB[1][(wc * 64 + j * 16 + lr) * BKP + lg * 8];
    }
#pragma unroll
    for (int i = 0; i < 4; i++)
#pragma unroll
      for (int j = 0; j < 4; j++) {
        acc[i][j] = mfma16(ah[i], bh[j], acc[i][j]);
        if (TERMS == 3) {
          acc[i][j] = mfma16(ah[i], bl[j], acc[i][j]);
          acc[i][j] = mfma16(al[i], bh[j], acc[i][j]);
        }
      }
    __syncthreads();
  }
  long long cOff = (long long)z * cStr;
#pragma unroll
  for (int i = 0; i < 4; i++)
#pragma unroll
    for (int j = 0; j < 4; j++)
#pragma unroll
      for (int r = 0; r < 4; r++) {
        int row = rT + wr * 64 + i * 16 + lg * 4 + r;  // C/D: row=(l>>4)*4+reg
        int col = cT + wc * 64 + j * 16 + lr;          //      col=l&15
        float v = acc[i][j][r];
        unsigned short hb = f2bf(v);
        Chi[cOff + (size_t)row * N + col] = hb;
        if (SPLIT_OUT) Clo[cOff + (size_t)row * N + col] = f2bf(v - bf2f(hb));
      }
}

// ---------------------------------------------------------------------------
// Fused flash attention, round 5: R3 skeleton + zero-VALU LDS addressing.
// LDS map (bytes):
//   [0,32768)        X hi [64 t][512B], stored byte = logical ^ ((row&7)<<4)
//   [32768,65536)    X lo (same swizzle)
//   [65536,98304)    VT [256 f][128B],  stored byte = logical ^ ((row&7)<<4)
//   [98304,114688)   P: per wave 2KB [16 q][128B], stored ^ (((row>>2)&3)<<4)
// All inner-loop LDS addresses = loop-invariant base VGPR + offset immediate:
//   X:  xkb[kc] + j*8192 (+32768 for lo)     (8 base regs, kt-invariant)
//   VT: vtb[tc] + jf*2048                    (2 base regs)
//   P:  prb + tc*64                          (1 base reg; key bits [4:5] only)
#define TT 64
#define ATTN_LDS 114688

__global__ __launch_bounds__(512, 2) void k_attn(
    const unsigned short* __restrict__ Yhi, const unsigned short* __restrict__ Ylo,
    const unsigned short* __restrict__ Xhi, const unsigned short* __restrict__ Xlo,
    const unsigned short* __restrict__ VT, float* __restrict__ Out) {
  extern __shared__ char smem[];

  // XCD-chunked swizzle (L2 discipline: 2 bh + 1 b per XCD concurrently).
  int obid = blockIdx.x;
  int swz = (obid & 7) * 64 + (obid >> 3);
  int qt = swz & 15, bh = swz >> 4;
  int b = bh >> 3;
  int tid = threadIdx.x, w = tid >> 6, l = tid & 63, lr = l & 15, lg = l >> 4;
  const unsigned short* Ybh_h = Yhi + (size_t)bh * (S_N * E_N);
  const unsigned short* Ybh_l = Ylo + (size_t)bh * (S_N * E_N);
  const unsigned short* Xb_h = Xhi + (size_t)b * (S_N * E_N);
  const unsigned short* Xb_l = Xlo + (size_t)b * (S_N * E_N);
  const unsigned short* Vbh = VT + (size_t)bh * (E_N * S_N);
  int qrow = qt * 128 + w * 16;

  // Staging source descriptors (inverse-swizzled global element offsets).
  int xsrc[4], vsrc[4];
#pragma unroll
  for (int i = 0; i < 4; i++) {
    int c = w * 4 + i;
    int row = 2 * c + (l >> 5), byt = (l & 31) * 16;
    xsrc[i] = row * E_N + ((byt ^ ((row & 7) << 4)) >> 1);
    int vrow = 8 * c + (l >> 3), vbyt = (l & 7) * 16;
    vsrc[i] = vrow * S_N + ((vbyt ^ ((vrow & 7) << 4)) >> 1);
  }

  // Hoisted LDS base addresses (all kt-invariant).
  int xkb[8];
#pragma unroll
  for (int kc = 0; kc < 8; kc++)
    xkb[kc] = lr * 512 + ((kc * 64 + lg * 16) ^ ((lr & 7) << 4));
  int vtb[2];
#pragma unroll
  for (int tc = 0; tc < 2; tc++)
    vtb[tc] = 65536 + lr * 128 + ((tc * 64 + lg * 16) ^ ((lr & 7) << 4));
  int prb = 98304 + w * 2048 + lr * 128 + ((lg * 16) ^ (((lr >> 2) & 3) << 4));
  int pwb = 98304 + w * 2048 + lg * 512;  // + r*128 + swizzled byte per write

  // Hoist Y fragments (16 rows x K=256, hi+lo) into registers.
  s16x8 yh[8], yl[8];
#pragma unroll
  for (int kc = 0; kc < 8; kc++) {
    yh[kc] = *(const s16x8*)(Ybh_h + (size_t)(qrow + lr) * E_N + kc * 32 + lg * 8);
    yl[kc] = *(const s16x8*)(Ybh_l + (size_t)(qrow + lr) * E_N + kc * 32 + lg * 8);
  }
  f32x4 o[16];
#pragma unroll
  for (int i = 0; i < 16; i++) o[i] = (f32x4){0.f, 0.f, 0.f, 0.f};
  float m2[4], lv[4];
#pragma unroll
  for (int r = 0; r < 4; r++) { m2[r] = -3.0e38f; lv[r] = 0.f; }

  const float C2 = 0.09016844005556021f;  // (1/16) * log2(e)

  for (int kt = 0; kt < S_N / TT; kt++) {
    __builtin_amdgcn_s_barrier();  // B1: all waves done reading previous tile

    // Stage X[kt] (hi+lo) and VT[kt] via async global->LDS.
#pragma unroll
    for (int i = 0; i < 4; i++) {
      int c = w * 4 + i;
      gload16(Xb_h + (size_t)kt * (TT * E_N) + xsrc[i], smem + c * 1024);
      gload16(Xb_l + (size_t)kt * (TT * E_N) + xsrc[i], smem + 32768 + c * 1024);
      gload16(Vbh + kt * TT + vsrc[i], smem + 65536 + c * 1024);
    }
    asm volatile("s_waitcnt vmcnt(0)" ::: "memory");
    __builtin_amdgcn_s_barrier();  // B2: staged data visible to all waves

    // S = Y . X^T (3-term split), raw units. Zero address VALU.
    f32x4 sc[4];
    __builtin_amdgcn_s_setprio(1);
#pragma unroll
    for (int j = 0; j < 4; j++) {
      f32x4 a = (f32x4){0.f, 0.f, 0.f, 0.f};
#pragma unroll
      for (int kc = 0; kc < 8; kc++) {
        s16x8 xh = *(const s16x8*)(smem + xkb[kc] + j * 8192);
        s16x8 xl = *(const s16x8*)(smem + xkb[kc] + j * 8192 + 32768);
        a = mfma16(yh[kc], xh, a);
        a = mfma16(yh[kc], xl, a);
        a = mfma16(yl[kc], xh, a);
      }
      sc[j] = a;
    }
    __builtin_amdgcn_s_setprio(0);

    // Online softmax, log2 domain. Lane holds rows lg*4+r, cols j*16+lr.
    float t2[4];
#pragma unroll
    for (int r = 0; r < 4; r++)
      t2[r] = fmaxf(fmaxf(sc[0][r], sc[1][r]), fmaxf(sc[2][r], sc[3][r])) * C2;

    // Defer-max via per-lane partial check (equivalent under __all).
    bool ok = (t2[0] <= m2[0] + 8.f) && (t2[1] <= m2[1] + 8.f) &&
              (t2[2] <= m2[2] + 8.f) && (t2[3] <= m2[3] + 8.f);
    if (!__all(ok)) {
      float fr[4];
#pragma unroll
      for (int r = 0; r < 4; r++) {
        float rm = dppmax16(t2[r]);          // true row max (16 col-lanes)
        float nm = fmaxf(m2[r], rm);
        fr[r] = exp2f(m2[r] - nm);
        m2[r] = nm;
        lv[r] *= fr[r];
      }
#pragma unroll
      for (int i = 0; i < 16; i++)
#pragma unroll
        for (int r = 0; r < 4; r++) o[i][r] *= fr[r];
    }

    float p[4][4];
#pragma unroll
    for (int j = 0; j < 4; j++)
#pragma unroll
      for (int r = 0; r < 4; r++)
        p[j][r] = exp2f(fmaf(sc[j][r], C2, -m2[r]));
#pragma unroll
    for (int r = 0; r < 4; r++)
      lv[r] += (p[0][r] + p[1][r]) + (p[2][r] + p[3][r]);  // per-lane partial

    // P -> LDS bf16 (wave-private; stored byte = logical ^ (((row>>2)&3)<<4)).
#pragma unroll
    for (int j = 0; j < 4; j++)
#pragma unroll
      for (int r = 0; r < 4; r++) {
        int byt = (32 * j + 2 * lr) ^ (lg << 4);  // key2(row)=row>>2&3 = lg
        *(unsigned short*)(smem + pwb + r * 128 + byt) = f2bf_fast(p[j][r]);
      }

    // O += P . VT  (bt-form; base + imm addressing, zero VALU)
    __builtin_amdgcn_s_setprio(1);
#pragma unroll
    for (int tc = 0; tc < 2; tc++) {
      s16x8 pa = *(const s16x8*)(smem + prb + tc * 64);
#pragma unroll
      for (int jf = 0; jf < 16; jf++) {
        s16x8 bv = *(const s16x8*)(smem + vtb[tc] + jf * 2048);
        o[jf] = mfma16(pa, bv, o[jf]);
      }
    }
    __builtin_amdgcn_s_setprio(0);
  }

  // Epilogue: finish lv sum-reduce, normalize, head-mean via atomics.
#pragma unroll
  for (int r = 0; r < 4; r++) lv[r] = dppsum16(lv[r]);
#pragma unroll
  for (int jf = 0; jf < 16; jf++)
#pragma unroll
    for (int r = 0; r < 4; r++) {
      float v = o[jf][r] / lv[r] * 0.125f;
      atomicAdd(&Out[((size_t)b * S_N + qrow + lg * 4 + r) * E_N + jf * 16 + lr], v);
    }
}

// ---------------------------------------------------------------------------
extern "C" void kernel_launch(void* const* d_in, const int* in_sizes, int n_in,
                              void* d_out, int out_size, void* d_ws, size_t ws_size,
                              hipStream_t stream) {
  const float* x = (const float*)d_in[0];
  const float* wq = (const float*)d_in[1];
  const float* wk = (const float*)d_in[2];
  const float* wv = (const float*)d_in[3];
  float* out = (float*)d_out;

  unsigned short* ws = (unsigned short*)d_ws;
  unsigned short* x_hi = ws;                       // [B,S,E]
  unsigned short* x_lo = x_hi + 2097152;
  unsigned short* wq_hi = x_lo + 2097152;          // [H,E,E]
  unsigned short* wq_lo = wq_hi + 524288;
  unsigned short* wk_hi = wq_lo + 524288;
  unsigned short* wk_lo = wk_hi + 524288;
  unsigned short* wvT = wk_lo + 524288;            // [H,E(f),E(e)]
  unsigned short* mt_hi = wvT + 524288;            // [H,E,E] = Wk.Wq^T
  unsigned short* mt_lo = mt_hi + 524288;
  unsigned short* y_hi = mt_lo + 524288;           // [B,H,S,E]
  unsigned short* y_lo = y_hi + 16777216;
  unsigned short* vt = y_lo + 16777216;            // [B,H,E(f),S(t)]

  hipMemsetAsync(d_out, 0, (size_t)out_size * sizeof(float), stream);

  k_split<<<2048, 256, 0, stream>>>(x, x_hi, x_lo, 524288);
  k_split<<<512, 256, 0, stream>>>(wq, wq_hi, wq_lo, 131072);
  k_split<<<512, 256, 0, stream>>>(wk, wk_hi, wk_lo, 131072);
  k_transpose_wv<<<dim3(8, 8, 8), 256, 0, stream>>>(wv, wvT);

  // MT_h = Wk_h . Wq_h^T
  k_gemm<3, 1><<<dim3(2, 2, 8), 256, 0, stream>>>(
      wk_hi, wk_lo, wq_hi, wq_lo, mt_hi, mt_lo, 256, 256,
      1, 8, 65536LL, 1, 8, 65536LL, 65536LL);
  // Y[b,h] = X_b . MT_h^T
  k_gemm<3, 1><<<dim3(16, 2, 32), 256, 0, stream>>>(
      x_hi, x_lo, mt_hi, mt_lo, y_hi, y_lo, 256, 256,
      8, 4, 524288LL, 1, 8, 65536LL, 524288LL);
  // VT[b,h] = WvT_h . X_b^T
  k_gemm<1, 0><<<dim3(2, 16, 32), 256, 0, stream>>>(
      wvT, wvT, x_hi, x_hi, vt, vt, 256, 2048,
      1, 8, 65536LL, 8, 4, 524288LL, 524288LL);

  hipFuncSetAttribute((const void*)k_attn, hipFuncAttributeMaxDynamicSharedMemorySize,
                      ATTN_LDS);
  k_attn<<<dim3(512), 512, ATTN_LDS, stream>>>(y_hi, y_lo, x_hi, x_lo, vt, out);
}